// Round 7
// baseline (1522.156 us; speedup 1.0000x reference)
//
#include <hip/hip_runtime.h>
#include <cstdint>

#define UNITS 128
#define GATES 512            // 4*UNITS
#define IN_DIM 128
#define BATCH 64
#define SEQ 2048
#define ROWS (BATCH * SEQ)   // 131072

typedef _Float16 f16;
typedef _Float16 f16x2 __attribute__((ext_vector_type(2)));
typedef _Float16 f16x8 __attribute__((ext_vector_type(8)));
typedef float    f32x4 __attribute__((ext_vector_type(4)));

static __device__ __forceinline__ float sigmoid_f(float x) {
    float e = __builtin_amdgcn_exp2f(-1.44269504f * x);
    return __builtin_amdgcn_rcpf(1.0f + e);
}
static __device__ __forceinline__ float tanh_f(float x) {
    float e = __builtin_amdgcn_exp2f(2.8853900817779268f * x);
    return 1.0f - 2.0f * __builtin_amdgcn_rcpf(1.0f + e);
}

// Workgroup barrier ordering LDS only (no vmcnt(0) drain of stores/prefetch).
static __device__ __forceinline__ void lds_barrier() {
    __asm__ volatile("s_waitcnt lgkmcnt(0)\n\ts_barrier" ::: "memory");
}

// ---------------------------------------------------------------------------
// Kernel 1: WxT[n][k] = (f16)Wx[k][n]
// ---------------------------------------------------------------------------
__global__ void wxt_kernel(const float* __restrict__ W,
                           f16* __restrict__ WxT) {
    int idx = blockIdx.x * 256 + threadIdx.x;     // over Wx (128x512)
    int k = idx >> 9, n = idx & 511;
    WxT[n * IN_DIM + k] = (f16)W[idx];
}

// ---------------------------------------------------------------------------
// Kernel 2: xp = data @ Wx + b, stored in the scan-consumer layout.
// Per (row, w):  f16-offset w*128 + j   (j = m16*4 + r', gates i,f; one b64
//                per scan q0-lane), and w*128 + 64 + l (gates o,g; one f16
//                per scan lane l).
// WxT staged to LDS in two 64-KiB phases — round-6 gemm re-pulled B from L2
// every nt iteration (2 MB/WG, ~2 GB total => the stubborn ~170 us).
// ---------------------------------------------------------------------------
__global__ __launch_bounds__(256) void xp_gemm(
        const float* __restrict__ A,      // data f32, ROWS x 128
        const f16*  __restrict__ WxT,     // 512 x 128 f16 (n-major)
        const float* __restrict__ bias,   // 512 f32
        f16* __restrict__ xp) {           // ROWS x 512 f16 (swizzled)
    __shared__ f16 Blds[256 * IN_DIM];    // 64 KiB: 16 n-tiles per phase

    const int wave = threadIdx.x >> 6;
    const int lane = threadIdx.x & 63;
    const int m16  = lane & 15;
    const int q    = lane >> 4;
    const int rowBase = blockIdx.x * 128 + wave * 32;

    f16x8 a[2][4];
    #pragma unroll
    for (int mc = 0; mc < 2; ++mc)
        #pragma unroll
        for (int ks = 0; ks < 4; ++ks) {
            const float* p = A + (size_t)(rowBase + mc * 16 + m16) * IN_DIM
                               + ks * 32 + q * 8;
            float4 lo = *(const float4*)p;
            float4 hi = *(const float4*)(p + 4);
            f16x8 v;
            v[0] = (f16)lo.x; v[1] = (f16)lo.y; v[2] = (f16)lo.z; v[3] = (f16)lo.w;
            v[4] = (f16)hi.x; v[5] = (f16)hi.y; v[6] = (f16)hi.z; v[7] = (f16)hi.w;
            a[mc][ks] = v;
        }

    for (int phase = 0; phase < 2; ++phase) {
        // Stage n = [phase*256, phase*256+256) of WxT -> LDS (coalesced b128).
        {
            const f16x8* src = (const f16x8*)(WxT + (size_t)phase * 256 * IN_DIM);
            f16x8* dst = (f16x8*)Blds;
            #pragma unroll
            for (int i = 0; i < 16; ++i)
                dst[i * 256 + threadIdx.x] = src[i * 256 + threadIdx.x];
        }
        __syncthreads();

        for (int ntl = 0; ntl < 16; ++ntl) {
            f16x8 bfr[4];
            #pragma unroll
            for (int ks = 0; ks < 4; ++ks)
                bfr[ks] = *(const f16x8*)(Blds + (ntl * 16 + m16) * IN_DIM
                                               + ks * 32 + q * 8);
            f32x4 acc0 = {0.f, 0.f, 0.f, 0.f}, acc1 = {0.f, 0.f, 0.f, 0.f};
            #pragma unroll
            for (int ks = 0; ks < 4; ++ks) {
                acc0 = __builtin_amdgcn_mfma_f32_16x16x32_f16(a[0][ks], bfr[ks], acc0, 0, 0, 0);
                acc1 = __builtin_amdgcn_mfma_f32_16x16x32_f16(a[1][ks], bfr[ks], acc1, 0, 0, 0);
            }
            const int c  = (phase * 16 + ntl) * 16 + m16;   // global column
            const int g  = c >> 7, w2 = (c >> 5) & 3;
            const int hi = (c >> 4) & 1, m = c & 15;
            const int off = (g < 2) ? (w2 * 128 + m * 4 + g * 2 + hi)
                                    : (w2 * 128 + 64 + (g - 2) * 32 + hi * 16 + m);
            const float bv = bias[c];
            #pragma unroll
            for (int r = 0; r < 4; ++r) {
                int row0 = rowBase + q * 4 + r;             // D: row = q*4+reg
                xp[(size_t)row0 * 512 + off]        = (f16)(acc0[r] + bv);
                xp[(size_t)(row0 + 16) * 512 + off] = (f16)(acc1[r] + bv);
            }
        }
        __syncthreads();   // before re-staging LDS
    }
}

// ---------------------------------------------------------------------------
// Kernel 3: HYBRID scan. 64 WGs (one sample), 256 threads (4 waves).
// Wave w owns cells [32w, 32w+32).
//  - Gates i,f (cols 0..255 slice) via MFMA: 16 instr/step (~310 cy matrix
//    pipe; round-6 measured the 32-instr variant at 620 cy = the floor).
//  - Gates o,g via fdot2 on the VALU (64/lane), co-issued with MFMA (m114).
//  xp enters via MFMA acc-init (reg0) + per-lane scalar; gate exchange via
//  3x shfl_xor; one lds_barrier per step.
// ---------------------------------------------------------------------------
__global__ __launch_bounds__(256, 1) void lstm_scan_hybrid(
        const float* __restrict__ W,      // 256 x 512 f32
        const f16* __restrict__ xp,       // swizzled, see xp_gemm
        float* __restrict__ out) {        // ROWS x 128 f32
    __shared__ __align__(16) f16 h_lds[2][UNITS];

    const int tid = threadIdx.x;
    const int b   = blockIdx.x;
    const int w   = tid >> 6;
    const int l   = tid & 63;
    const int m16 = l & 15;
    const int q   = l >> 4;
    const int h32 = l >> 5;              // 0: o-gate col, 1: g-gate col
    const int c32 = l & 31;

    // MFMA B-frags, gates i,f: whb[r][kt]; r: 0=i-lo 1=i-hi 2=f-lo 3=f-hi.
    f16x8 whb[4][4];
    #pragma unroll
    for (int r = 0; r < 4; ++r) {
        const int colb = 128 * (r >> 1) + 32 * w + 16 * (r & 1) + m16;
        #pragma unroll
        for (int kt = 0; kt < 4; ++kt) {
            f16x8 v;
            #pragma unroll
            for (int j = 0; j < 8; ++j)
                v[j] = (f16)W[(size_t)(IN_DIM + kt * 32 + q * 8 + j) * GATES + colb];
            whb[r][kt] = v;
        }
    }
    // fdot2 weights, gates o,g: this lane's single column.
    const int colf = 256 + 128 * h32 + 32 * w + c32;
    f16x2 wv[64];
    #pragma unroll
    for (int k = 0; k < 64; ++k)
        wv[k] = f16x2{(f16)W[(size_t)(IN_DIM + 2 * k) * GATES + colf],
                      (f16)W[(size_t)(IN_DIM + 2 * k + 1) * GATES + colf]};

    float cs0 = 1.0f, cs1 = 1.0f;                  // c0 = ones (2 cells/q0-lane)
    if (tid < UNITS) h_lds[0][tid] = (f16)0.f;     // h0 = zeros

    const char* xq = (const char*)xp + (size_t)b * SEQ * 1024 + w * 256;
    // prefetch distance 2:  LA = b64 (zi0,zi1,zf0,zf1), LB = scalar f16 (o/g).
    uint2 LA0 = *(const uint2*)(xq + m16 * 8);
    uint2 LA1 = *(const uint2*)(xq + 1024 + m16 * 8);
    f16   LB0 = *(const f16*)(xq + 128 + l * 2);
    f16   LB1 = *(const f16*)(xq + 1024 + 128 + l * 2);
    __syncthreads();

    for (int t = 0; t < SEQ; ++t) {
        const int cur = t & 1, nxt = cur ^ 1;
        uint2 LAc = LA0; f16 LBc = LB0;
        LA0 = LA1; LB0 = LB1;
        {
            int t2 = (t + 2 < SEQ) ? (t + 2) : (SEQ - 1);
            LA1 = *(const uint2*)(xq + (size_t)t2 * 1024 + m16 * 8);
            LB1 = *(const f16*)(xq + (size_t)t2 * 1024 + 128 + l * 2);
        }

        // --- LDS h reads: 4 A-frag b128 (computed addr) + 16 b128 broadcast.
        const char* hbase = (const char*)(&h_lds[cur][0]);
        f16x8 af[4];
        #pragma unroll
        for (int kt = 0; kt < 4; ++kt)
            af[kt] = *(const f16x8*)(hbase + kt * 64 + q * 16);
        uint4 hb[16];
        #pragma unroll
        for (int i = 0; i < 16; ++i)
            hb[i] = ((const uint4*)hbase)[i];

        // --- MFMA half (i,f): acc init reg0 = xp value (rows 4,8,12 garbage).
        f16x2 lax = __builtin_bit_cast(f16x2, LAc.x);  // (zi0, zi1) xp part
        f16x2 lay = __builtin_bit_cast(f16x2, LAc.y);  // (zf0, zf1) xp part
        f32x4 acc[4];
        acc[0] = f32x4{(float)lax[0], 0.f, 0.f, 0.f};
        acc[1] = f32x4{(float)lax[1], 0.f, 0.f, 0.f};
        acc[2] = f32x4{(float)lay[0], 0.f, 0.f, 0.f};
        acc[3] = f32x4{(float)lay[1], 0.f, 0.f, 0.f};
        #pragma unroll
        for (int r = 0; r < 4; ++r)
            #pragma unroll
            for (int kt = 0; kt < 4; ++kt)
                acc[r] = __builtin_amdgcn_mfma_f32_16x16x32_f16(af[kt], whb[r][kt], acc[r], 0, 0, 0);

        // --- fdot2 half (o,g): 64 fdot2 in 4 independent chains.
        float za = 0.f, zb = 0.f, zc = 0.f, zd = 0.f;
        #pragma unroll
        for (int i = 0; i < 4; ++i) {
            za = __builtin_amdgcn_fdot2(__builtin_bit_cast(f16x2, hb[i].x),      wv[4 * i],      za, false);
            za = __builtin_amdgcn_fdot2(__builtin_bit_cast(f16x2, hb[i].y),      wv[4 * i + 1],  za, false);
            za = __builtin_amdgcn_fdot2(__builtin_bit_cast(f16x2, hb[i].z),      wv[4 * i + 2],  za, false);
            za = __builtin_amdgcn_fdot2(__builtin_bit_cast(f16x2, hb[i].w),      wv[4 * i + 3],  za, false);
            zb = __builtin_amdgcn_fdot2(__builtin_bit_cast(f16x2, hb[i + 4].x),  wv[16 + 4 * i],     zb, false);
            zb = __builtin_amdgcn_fdot2(__builtin_bit_cast(f16x2, hb[i + 4].y),  wv[16 + 4 * i + 1], zb, false);
            zb = __builtin_amdgcn_fdot2(__builtin_bit_cast(f16x2, hb[i + 4].z),  wv[16 + 4 * i + 2], zb, false);
            zb = __builtin_amdgcn_fdot2(__builtin_bit_cast(f16x2, hb[i + 4].w),  wv[16 + 4 * i + 3], zb, false);
            zc = __builtin_amdgcn_fdot2(__builtin_bit_cast(f16x2, hb[i + 8].x),  wv[32 + 4 * i],     zc, false);
            zc = __builtin_amdgcn_fdot2(__builtin_bit_cast(f16x2, hb[i + 8].y),  wv[32 + 4 * i + 1], zc, false);
            zc = __builtin_amdgcn_fdot2(__builtin_bit_cast(f16x2, hb[i + 8].z),  wv[32 + 4 * i + 2], zc, false);
            zc = __builtin_amdgcn_fdot2(__builtin_bit_cast(f16x2, hb[i + 8].w),  wv[32 + 4 * i + 3], zc, false);
            zd = __builtin_amdgcn_fdot2(__builtin_bit_cast(f16x2, hb[i + 12].x), wv[48 + 4 * i],     zd, false);
            zd = __builtin_amdgcn_fdot2(__builtin_bit_cast(f16x2, hb[i + 12].y), wv[48 + 4 * i + 1], zd, false);
            zd = __builtin_amdgcn_fdot2(__builtin_bit_cast(f16x2, hb[i + 12].z), wv[48 + 4 * i + 2], zd, false);
            zd = __builtin_amdgcn_fdot2(__builtin_bit_cast(f16x2, hb[i + 12].w), wv[48 + 4 * i + 3], zd, false);
        }
        float zB = (float)LBc + ((za + zb) + (zc + zd));   // this lane's o or g

        // Gate exchange within the wave (no barrier):
        float v16 = __shfl_xor(zB, 16, 64);   // q0-lane: zo(cell 16+m16)
        float v32 = __shfl_xor(zB, 32, 64);   // q0-lane: zg(cell m16)
        float v48 = __shfl_xor(zB, 48, 64);   // q0-lane: zg(cell 16+m16)

        if (l < 16) {  // q==0: owns cells 32w+m16 and 32w+16+m16
            float zi0 = acc[0][0], zi1 = acc[1][0];
            float zf0 = acc[2][0], zf1 = acc[3][0];
            float zo0 = zB,  zo1 = v16;
            float zg0 = v32, zg1 = v48;
            cs0 = sigmoid_f(zf0) * cs0 + sigmoid_f(zi0) * tanh_f(zg0);
            cs1 = sigmoid_f(zf1) * cs1 + sigmoid_f(zi1) * tanh_f(zg1);
            float h0 = sigmoid_f(zo0) * tanh_f(cs0);
            float h1 = sigmoid_f(zo1) * tanh_f(cs1);
            h_lds[nxt][32 * w + m16]      = (f16)h0;
            h_lds[nxt][32 * w + 16 + m16] = (f16)h1;
            float* op = out + ((size_t)b * SEQ + t) * UNITS + 32 * w;
            op[m16]      = h0;
            op[16 + m16] = h1;
        }
        lds_barrier();
    }
}

// ---------------------------------------------------------------------------
// Fallback (ws too small): fused fdot2 scan, Wx in registers (round-5 shape).
// ---------------------------------------------------------------------------
__global__ __launch_bounds__(256, 1) void lstm_scan_fused(
        const float* __restrict__ W,
        const float* __restrict__ bias,
        const float* __restrict__ data,
        float* __restrict__ out) {
    __shared__ __align__(16) f16 h_lds[2][UNITS];
    __shared__ __align__(16) f16 x_lds[2][UNITS];

    const int tid  = threadIdx.x;
    const int b    = blockIdx.x;
    const int wave = tid >> 6;
    const int lane = tid & 63;
    const int half = lane >> 5;
    const int cell = wave * 32 + (lane & 31);
    const int c0   = cell + half * 256;
    const int c1   = c0 + 128;

    f16x2 wh0[64], wh1[64], wxa[64], wxb[64];
    #pragma unroll
    for (int k = 0; k < 64; ++k) {
        wh0[k] = f16x2{(f16)W[(size_t)(IN_DIM + 2 * k) * GATES + c0],
                       (f16)W[(size_t)(IN_DIM + 2 * k + 1) * GATES + c0]};
        wh1[k] = f16x2{(f16)W[(size_t)(IN_DIM + 2 * k) * GATES + c1],
                       (f16)W[(size_t)(IN_DIM + 2 * k + 1) * GATES + c1]};
        wxa[k] = f16x2{(f16)W[(size_t)(2 * k) * GATES + c0],
                       (f16)W[(size_t)(2 * k + 1) * GATES + c0]};
        wxb[k] = f16x2{(f16)W[(size_t)(2 * k) * GATES + c1],
                       (f16)W[(size_t)(2 * k + 1) * GATES + c1]};
    }
    float bb0 = bias[c0], bb1 = bias[c1];

    float c = 1.0f;
    if (tid < UNITS) {
        h_lds[0][tid] = (f16)0.f;
        x_lds[0][tid] = (f16)data[(size_t)b * SEQ * IN_DIM + tid];
    }
    __syncthreads();

    for (int t = 0; t < SEQ; ++t) {
        const int cur = t & 1, nxt = cur ^ 1;
        float a00 = bb0, a01 = 0.f, a10 = bb1, a11 = 0.f;

        const uint4* xsrc = (const uint4*)(&x_lds[cur][0]);
        const uint4* hsrc = (const uint4*)(&h_lds[cur][0]);
        uint4 xb[16], hb[16];
        #pragma unroll
        for (int i = 0; i < 16; ++i) { xb[i] = xsrc[i]; hb[i] = hsrc[i]; }
        #pragma unroll
        for (int i = 0; i < 16; ++i) {
            f16x2 x0 = __builtin_bit_cast(f16x2, xb[i].x);
            f16x2 x1 = __builtin_bit_cast(f16x2, xb[i].y);
            f16x2 x2 = __builtin_bit_cast(f16x2, xb[i].z);
            f16x2 x3 = __builtin_bit_cast(f16x2, xb[i].w);
            f16x2 h0 = __builtin_bit_cast(f16x2, hb[i].x);
            f16x2 h1 = __builtin_bit_cast(f16x2, hb[i].y);
            f16x2 h2 = __builtin_bit_cast(f16x2, hb[i].z);
            f16x2 h3 = __builtin_bit_cast(f16x2, hb[i].w);
            const int k = 4 * i;
            if (i < 8) {
                a00 = __builtin_amdgcn_fdot2(x0, wxa[k],     a00, false);
                a10 = __builtin_amdgcn_fdot2(x0, wxb[k],     a10, false);
                a00 = __builtin_amdgcn_fdot2(x1, wxa[k + 1], a00, false);
                a10 = __builtin_amdgcn_fdot2(x1, wxb[k + 1], a10, false);
                a00 = __builtin_amdgcn_fdot2(x2, wxa[k + 2], a00, false);
                a10 = __builtin_amdgcn_fdot2(x2, wxb[k + 2], a10, false);
                a00 = __builtin_amdgcn_fdot2(x3, wxa[k + 3], a00, false);
                a10 = __builtin_amdgcn_fdot2(x3, wxb[k + 3], a10, false);
                a00 = __builtin_amdgcn_fdot2(h0, wh0[k],     a00, false);
                a10 = __builtin_amdgcn_fdot2(h0, wh1[k],     a10, false);
                a00 = __builtin_amdgcn_fdot2(h1, wh0[k + 1], a00, false);
                a10 = __builtin_amdgcn_fdot2(h1, wh1[k + 1], a10, false);
                a00 = __builtin_amdgcn_fdot2(h2, wh0[k + 2], a00, false);
                a10 = __builtin_amdgcn_fdot2(h2, wh1[k + 2], a10, false);
                a00 = __builtin_amdgcn_fdot2(h3, wh0[k + 3], a00, false);
                a10 = __builtin_amdgcn_fdot2(h3, wh1[k + 3], a10, false);
            } else {
                a01 = __builtin_amdgcn_fdot2(x0, wxa[k],     a01, false);
                a11 = __builtin_amdgcn_fdot2(x0, wxb[k],     a11, false);
                a01 = __builtin_amdgcn_fdot2(x1, wxa[k + 1], a01, false);
                a11 = __builtin_amdgcn_fdot2(x1, wxb[k + 1], a11, false);
                a01 = __builtin_amdgcn_fdot2(x2, wxa[k + 2], a01, false);
                a11 = __builtin_amdgcn_fdot2(x2, wxb[k + 2], a11, false);
                a01 = __builtin_amdgcn_fdot2(x3, wxa[k + 3], a01, false);
                a11 = __builtin_amdgcn_fdot2(x3, wxb[k + 3], a11, false);
                a01 = __builtin_amdgcn_fdot2(h0, wh0[k],     a01, false);
                a11 = __builtin_amdgcn_fdot2(h0, wh1[k],     a11, false);
                a01 = __builtin_amdgcn_fdot2(h1, wh0[k + 1], a01, false);
                a11 = __builtin_amdgcn_fdot2(h1, wh1[k + 1], a11, false);
                a01 = __builtin_amdgcn_fdot2(h2, wh0[k + 2], a01, false);
                a11 = __builtin_amdgcn_fdot2(h2, wh1[k + 2], a11, false);
                a01 = __builtin_amdgcn_fdot2(h3, wh0[k + 3], a01, false);
                a11 = __builtin_amdgcn_fdot2(h3, wh1[k + 3], a11, false);
            }
        }
        float z0 = a00 + a01, z1 = a10 + a11;
        float s0 = sigmoid_f(z0);
        float s1 = (half == 0) ? sigmoid_f(z1) : tanh_f(z1);
        float p0 = __shfl_xor(s0, 32, 64);
        float p1 = __shfl_xor(s1, 32, 64);
        if (half == 0) {
            c = s1 * c + s0 * p1;
            float h = p0 * tanh_f(c);
            h_lds[nxt][cell] = (f16)h;
            out[((size_t)b * SEQ + t) * UNITS + cell] = h;
        }
        if (tid < UNITS) {
            int t1 = (t + 1 < SEQ) ? (t + 1) : t;
            x_lds[nxt][tid] = (f16)data[(size_t)b * SEQ * IN_DIM
                                        + (size_t)t1 * IN_DIM + tid];
        }
        lds_barrier();
    }
}

// ---------------------------------------------------------------------------
extern "C" void kernel_launch(void* const* d_in, const int* in_sizes, int n_in,
                              void* d_out, int out_size, void* d_ws, size_t ws_size,
                              hipStream_t stream) {
    const float* data = (const float*)d_in[0];   // f32 (64,2048,128)
    const float* W    = (const float*)d_in[1];   // f32 (256,512)
    const float* bias = (const float*)d_in[2];   // f32 (512,)
    float* out = (float*)d_out;                  // f32 (64,2048,128)

    const size_t wxt_bytes = (size_t)GATES * IN_DIM * sizeof(f16);  // 128 KiB
    const size_t xp_bytes  = (size_t)ROWS * GATES * sizeof(f16);    // 128 MiB
    if (ws_size >= wxt_bytes + xp_bytes) {
        f16* WxT = (f16*)d_ws;
        f16* xp  = (f16*)((char*)d_ws + wxt_bytes);
        hipLaunchKernelGGL(wxt_kernel, dim3(256), dim3(256), 0, stream, W, WxT);
        hipLaunchKernelGGL(xp_gemm, dim3(ROWS / 128), dim3(256), 0, stream,
                           data, WxT, bias, xp);
        hipLaunchKernelGGL(lstm_scan_hybrid, dim3(BATCH), dim3(256), 0, stream,
                           W, xp, out);
    } else {
        hipLaunchKernelGGL(lstm_scan_fused, dim3(BATCH), dim3(256), 0, stream,
                           W, bias, data, out);
    }
}